// Round 1
// baseline (765.710 us; speedup 1.0000x reference)
//
#include <hip/hip_runtime.h>
#include <math.h>

#define N_NODES 21
#define NODE_FEAT 128
#define N_ACTIONS 256

// ws float layout:
//   [0, 448)     v (441 used, 7 pad)
//   [448, 960)   acc1 (512)
//   [960, 1472)  acc2 (512)
//   [1472, 1728) acc3 (256)
#define WS_V    0
#define WS_ACC1 448
#define WS_ACC2 960
#define WS_ACC3 1472

// ---------------- Kernel 1: GCN part (single block) ----------------
__global__ __launch_bounds__(512) void gcn_kernel(
    const float* __restrict__ state,      // [B,21,128], only batch 0 used
    const int*   __restrict__ edge_index, // [2,128]
    const float* __restrict__ W1,         // [128,21]
    const float* __restrict__ b1,         // [21]
    const float* __restrict__ W2,         // [21,21]
    const float* __restrict__ b2,         // [21]
    float* __restrict__ ws)
{
    __shared__ float sA[441];
    __shared__ float sX[N_NODES * NODE_FEAT];   // 2688
    __shared__ float sW1[NODE_FEAT * 21];       // 2688
    __shared__ float sW2[441];
    __shared__ float sh[441];
    __shared__ float sg[441];
    __shared__ float dinv[N_NODES];

    const int t = threadIdx.x;

    // zero adjacency
    if (t < 441) sA[t] = 0.0f;
    __syncthreads();

    // scatter-add edges: A[row,col] += 1
    if (t < 128) {
        int r = edge_index[t];         // edge_index[0][t]
        int c = edge_index[128 + t];   // edge_index[1][t]
        atomicAdd(&sA[r * 21 + c], 1.0f);
    }
    __syncthreads();

    // self loops
    if (t < 21) sA[t * 21 + t] += 1.0f;
    __syncthreads();

    // deg = column sums (axis=0); dinv = 1/sqrt(deg) (deg >= 1 from self loop)
    if (t < 21) {
        float d = 0.0f;
        for (int i = 0; i < 21; ++i) d += sA[i * 21 + t];
        dinv[t] = 1.0f / sqrtf(d);
    }
    __syncthreads();

    // A_norm[i,j] = dinv[i]*A[i,j]*dinv[j]
    if (t < 441) {
        int i = t / 21, j = t % 21;
        sA[t] = dinv[i] * sA[t] * dinv[j];
    }

    // stage X (batch 0) and W1, W2 into LDS
    for (int i = t; i < N_NODES * NODE_FEAT; i += 512) sX[i] = state[i];
    for (int i = t; i < NODE_FEAT * 21; i += 512)      sW1[i] = W1[i];
    if (t < 441) sW2[t] = W2[t];
    __syncthreads();

    // h1[n,k] = sum_f X[n,f] * W1[f,k]
    if (t < 441) {
        int n = t / 21, k = t % 21;
        float s = 0.0f;
        for (int f = 0; f < NODE_FEAT; ++f) s += sX[n * NODE_FEAT + f] * sW1[f * 21 + k];
        sh[t] = s;
    }
    __syncthreads();

    // g1[i,k] = b1[k] + sum_j A[i,j] * h1[j,k]
    if (t < 441) {
        int i = t / 21, k = t % 21;
        float s = b1[k];
        for (int j = 0; j < 21; ++j) s += sA[i * 21 + j] * sh[j * 21 + k];
        sg[t] = s;
    }
    __syncthreads();

    // h2[n,k] = sum_f g1[n,f] * W2[f,k]
    if (t < 441) {
        int n = t / 21, k = t % 21;
        float s = 0.0f;
        for (int f = 0; f < 21; ++f) s += sg[n * 21 + f] * sW2[f * 21 + k];
        sh[t] = s;
    }
    __syncthreads();

    // v[i*21+k] = b2[k] + sum_j A[i,j] * h2[j,k]
    if (t < 441) {
        int i = t / 21, k = t % 21;
        float s = b2[k];
        for (int j = 0; j < 21; ++j) s += sA[i * 21 + j] * sh[j * 21 + k];
        ws[WS_V + t] = s;
    }
    if (t >= 441 && t < 448) ws[WS_V + t] = 0.0f;

    // zero split-K accumulators (acc1, acc2: 512 each; acc3: 256)
    ws[WS_ACC1 + t] = 0.0f;                 // t in [0,512)
    ws[WS_ACC2 + t] = 0.0f;
    if (t < 256) ws[WS_ACC3 + t] = 0.0f;
}

// ---------------- Kernel 2: FC1 split-K (441 -> 512) ----------------
// 63 blocks x 256 threads, 7 rows per block, 2 outputs per thread
__global__ __launch_bounds__(256) void fc1_kernel(
    const float* __restrict__ Wf1,   // [441,512]
    float* __restrict__ ws)
{
    const float* v = ws + WS_V;
    float* acc1 = ws + WS_ACC1;
    const int b = blockIdx.x, t = threadIdx.x;
    const int r0 = b * 7;

    float vl[7];
    #pragma unroll
    for (int r = 0; r < 7; ++r) vl[r] = v[r0 + r];

    float s0 = 0.0f, s1 = 0.0f;
    #pragma unroll
    for (int r = 0; r < 7; ++r) {
        const float* row = Wf1 + (size_t)(r0 + r) * 512;
        s0 += vl[r] * row[t];
        s1 += vl[r] * row[t + 256];
    }
    atomicAdd(&acc1[t], s0);
    atomicAdd(&acc1[t + 256], s1);
}

// ---------------- Kernel 3: FC2 split-K (512 -> 512), fuses relu(acc1+bf1) ----------------
// 64 blocks x 256 threads, 8 rows per block
__global__ __launch_bounds__(256) void fc2_kernel(
    const float* __restrict__ Wf2,   // [512,512]
    const float* __restrict__ bf1,   // [512]
    float* __restrict__ ws)
{
    const float* acc1 = ws + WS_ACC1;
    float* acc2 = ws + WS_ACC2;
    const int b = blockIdx.x, t = threadIdx.x;
    const int r0 = b * 8;

    float x1[8];
    #pragma unroll
    for (int r = 0; r < 8; ++r) {
        float a = acc1[r0 + r] + bf1[r0 + r];
        x1[r] = a > 0.0f ? a : 0.0f;
    }

    float s0 = 0.0f, s1 = 0.0f;
    #pragma unroll
    for (int r = 0; r < 8; ++r) {
        const float* row = Wf2 + (size_t)(r0 + r) * 512;
        s0 += x1[r] * row[t];
        s1 += x1[r] * row[t + 256];
    }
    atomicAdd(&acc2[t], s0);
    atomicAdd(&acc2[t + 256], s1);
}

// ---------------- Kernel 4: FC3 split-K (512 -> 256), fuses relu(acc2+bf2) ----------------
// 32 blocks x 256 threads, 16 rows per block, 1 output per thread
__global__ __launch_bounds__(256) void fc3_kernel(
    const float* __restrict__ Wf3,   // [512,256]
    const float* __restrict__ bf2,   // [512]
    float* __restrict__ ws)
{
    const float* acc2 = ws + WS_ACC2;
    float* acc3 = ws + WS_ACC3;
    const int b = blockIdx.x, t = threadIdx.x;
    const int r0 = b * 16;

    float s = 0.0f;
    #pragma unroll
    for (int r = 0; r < 16; ++r) {
        float a = acc2[r0 + r] + bf2[r0 + r];
        a = a > 0.0f ? a : 0.0f;
        s += a * Wf3[(size_t)(r0 + r) * 256 + t];
    }
    atomicAdd(&acc3[t], s);
}

// ---------------- Kernel 5: finalize out = relu(acc3 + bf3) ----------------
__global__ __launch_bounds__(256) void finish_kernel(
    const float* __restrict__ bf3,   // [256]
    const float* __restrict__ ws,
    float* __restrict__ out)
{
    const int t = threadIdx.x;
    float a = ws[WS_ACC3 + t] + bf3[t];
    out[t] = a > 0.0f ? a : 0.0f;
}

extern "C" void kernel_launch(void* const* d_in, const int* in_sizes, int n_in,
                              void* d_out, int out_size, void* d_ws, size_t ws_size,
                              hipStream_t stream)
{
    const float* state      = (const float*)d_in[0];
    const int*   edge_index = (const int*)  d_in[1];
    const float* W1  = (const float*)d_in[2];
    const float* b1  = (const float*)d_in[3];
    const float* W2  = (const float*)d_in[4];
    const float* b2  = (const float*)d_in[5];
    const float* Wf1 = (const float*)d_in[6];
    const float* bf1 = (const float*)d_in[7];
    const float* Wf2 = (const float*)d_in[8];
    const float* bf2 = (const float*)d_in[9];
    const float* Wf3 = (const float*)d_in[10];
    const float* bf3 = (const float*)d_in[11];

    float* ws  = (float*)d_ws;
    float* out = (float*)d_out;

    gcn_kernel<<<1, 512, 0, stream>>>(state, edge_index, W1, b1, W2, b2, ws);
    fc1_kernel<<<63, 256, 0, stream>>>(Wf1, ws);
    fc2_kernel<<<64, 256, 0, stream>>>(Wf2, bf1, ws);
    fc3_kernel<<<32, 256, 0, stream>>>(Wf3, bf2, ws);
    finish_kernel<<<1, 256, 0, stream>>>(bf3, ws, out);
}